// Round 8
// baseline (1155.475 us; speedup 1.0000x reference)
//
#include <hip/hip_runtime.h>
#include <hip/hip_bf16.h>

typedef __bf16 bf16;
typedef __attribute__((ext_vector_type(8))) __bf16 bf16x8;
typedef __attribute__((ext_vector_type(4))) float f32x4;

#define NBLK 256  // radix chunks == scanA block size (bucket-aligned scan)

// unpack 8 packed bf16 (uint4) -> two f32x4
__device__ inline void unpack8(uint4 r, f32x4& a, f32x4& b) {
  a.x = __uint_as_float(r.x << 16);
  a.y = __uint_as_float(r.x & 0xffff0000u);
  a.z = __uint_as_float(r.y << 16);
  a.w = __uint_as_float(r.y & 0xffff0000u);
  b.x = __uint_as_float(r.z << 16);
  b.y = __uint_as_float(r.z & 0xffff0000u);
  b.z = __uint_as_float(r.w << 16);
  b.w = __uint_as_float(r.w & 0xffff0000u);
}

// Fused setup: blocks [0,NBLK) histogram; [NBLK,NBLK+128) pack B1/B2; rest cvt x->xb.
// (R6 proven form. R7's direct-scatter experiment REVERTED: random 4 B global
// scatter writes showed 83 MB HBM WRITE_SIZE for a 4.8 MB array — partial-line
// writeback amplification at ~0.9 TB/s => 100 us. Bucketed radix restores write
// locality.)
__global__ __launch_bounds__(256) void setup_k(const float* __restrict__ x,
                                               const int* __restrict__ dst,
                                               const float* __restrict__ W1l,
                                               const float* __restrict__ W1r,
                                               const float* __restrict__ W2l,
                                               const float* __restrict__ W2r,
                                               bf16* __restrict__ xb,
                                               bf16* __restrict__ B1,
                                               bf16* __restrict__ B2,
                                               int* __restrict__ hist,
                                               int E, int nb, int N, int Np) {
  __shared__ int h[1024];
  int t = threadIdx.x;
  if (blockIdx.x < NBLK) {
    for (int i = t; i < nb; i += 256) h[i] = 0;
    __syncthreads();
    int chunk = (E + NBLK - 1) / NBLK;
    int s = blockIdx.x * chunk, e = min(E, s + chunk);
    for (int i = s + t; i < e; i += 256) atomicAdd(&h[dst[i] >> 7], 1);
    __syncthreads();
    for (int i = t; i < nb; i += 256) hist[(long)i * NBLK + blockIdx.x] = h[i];
  } else if (blockIdx.x < NBLK + 128) {
    int gid = (blockIdx.x - NBLK) * 256 + t;  // 0..32767
    if (gid < 16384) {
      int c = gid >> 7, k = gid & 127;
      float v = (k < 64) ? W1l[c * 64 + k] : W1r[c * 64 + (k - 64)];
      B1[gid] = (bf16)v;
    } else {
      int idx = gid - 16384;
      int n = idx >> 7, k = idx & 127;
      float v = (n < 64) ? W2l[n * 128 + k] : W2r[(n - 64) * 128 + k];
      B2[idx] = (bf16)v;
    }
  } else {
    int gid = (blockIdx.x - NBLK - 128) * 256 + t;  // one per 4 elems
    long base = (long)gid * 4;
    if (base >= (long)Np * 64) return;
    if (base < (long)N * 64) {
      f32x4 v = *(const f32x4*)(x + base);
      bf16 o[4] = {(bf16)v.x, (bf16)v.y, (bf16)v.z, (bf16)v.w};
      *(ulong1*)(xb + base) = *(ulong1*)o;
    } else {
      bf16 o[4] = {(bf16)0.0f, (bf16)0.0f, (bf16)0.0f, (bf16)0.0f};
      *(ulong1*)(xb + base) = *(ulong1*)o;
    }
  }
}

// scanA: one block per bucket; exclusive scan of the bucket's 256 chunk counts
// in place; bucket total -> bsum[bucket].
__global__ __launch_bounds__(256) void scanA_k(int* __restrict__ hist,
                                               int* __restrict__ bsum) {
  __shared__ int sd[256];
  int t = threadIdx.x;
  int idx = blockIdx.x * 256 + t;
  int v = hist[idx];
  sd[t] = v;
  __syncthreads();
#pragma unroll
  for (int off = 1; off < 256; off <<= 1) {
    int tv = (t >= off) ? sd[t - off] : 0;
    __syncthreads();
    if (t >= off) sd[t] += tv;
    __syncthreads();
  }
  hist[idx] = sd[t] - v;  // bucket-local exclusive prefix
  if (t == 255) bsum[blockIdx.x] = sd[255];
}

// scanB: single-block in-place exclusive scan of bsum (nb <= 1024).
__global__ __launch_bounds__(1024) void scanB_k(int* __restrict__ bsum, int nb) {
  __shared__ int sd[1024];
  int t = threadIdx.x;
  int v = (t < nb) ? bsum[t] : 0;
  sd[t] = v;
  __syncthreads();
#pragma unroll
  for (int off = 1; off < 1024; off <<= 1) {
    int tv = (t >= off) ? sd[t - off] : 0;
    __syncthreads();
    if (t >= off) sd[t] += tv;
    __syncthreads();
  }
  if (t < nb) bsum[t] = sd[t] - v;
}

// Pass 2: re-read chunk, LDS cursors = bsum[b] + hist[b][chunk], write packed
// records (src<<7 | local-dst) into bucket regions.
__global__ __launch_bounds__(512) void scat_k(const int* __restrict__ src,
                                              const int* __restrict__ dst,
                                              const int* __restrict__ hist,
                                              const int* __restrict__ bsum,
                                              unsigned* __restrict__ ebuf, int E, int nb) {
  __shared__ int cur[1024];
  for (int i = threadIdx.x; i < nb; i += 512)
    cur[i] = bsum[i] + hist[(long)i * NBLK + blockIdx.x];
  __syncthreads();
  int chunk = (E + NBLK - 1) / NBLK;
  int s = blockIdx.x * chunk, e = min(E, s + chunk);
  for (int i = s + threadIdx.x; i < e; i += 512) {
    int d = dst[i];
    int pos = atomicAdd(&cur[d >> 7], 1);
    ebuf[pos] = ((unsigned)src[i] << 7) | (unsigned)(d & 127);
  }
}

// ---- R8: fused bucket aggregation (replaces csr_k + gather-style agg) ----
// One block per bucket. Edges are already grouped to this bucket's 128 nodes
// by scat_k; no within-bucket sort is needed for a sum. 8 lanes gather one
// edge's 128 B row; f32 LDS atomicAdd into acc[localdst][feat]. Wins vs the
// old csr+gather: csr's E-read+sort+E-write gone, nbr/rowptr gone, and the
// wave-per-node slot padding (16 slots for avg degree 12 -> ~25% wasted
// gathers) gone. acc row stride 65 (odd) -> ds_add bank (r+8f+j)%32 spreads
// 64 lanes 2-way (free, m136). 33.3 KB LDS -> 4 blocks/CU at 512 threads.
__global__ __launch_bounds__(512) void bagg1_k(const bf16* __restrict__ xb,
                                               const unsigned* __restrict__ ebuf,
                                               const int* __restrict__ bsum,
                                               bf16* __restrict__ A1, int nb, int E) {
  __shared__ float acc[128 * 65];
  __shared__ int cnt[128];
  int b = blockIdx.x, t = threadIdx.x;
  int s = bsum[b];
  int e = (b + 1 < nb) ? bsum[b + 1] : E;
  for (int i = t; i < 128 * 65; i += 512) acc[i] = 0.0f;
  if (t < 128) cnt[t] = 0;
  __syncthreads();
  int g = t >> 3, f = t & 7;  // 64 edge-groups x 8 feat-lanes
  // depth-2 pipelined edge loop (64 edges/round), mirrors proven R2 c0/c1 form
  bool v0 = (s + g) < e;
  unsigned r0 = 0;
  uint4 row0 = make_uint4(0u, 0u, 0u, 0u);
  if (v0) {
    r0 = ebuf[s + g];
    row0 = *(const uint4*)(xb + (long)(r0 >> 7) * 64 + f * 8);
  }
  for (int base = s; base < e; base += 64) {
    int i1 = base + 64 + g;
    bool v1 = i1 < e;
    unsigned r1 = 0;
    uint4 row1 = make_uint4(0u, 0u, 0u, 0u);
    if (v1) {
      r1 = ebuf[i1];
      row1 = *(const uint4*)(xb + (long)(r1 >> 7) * 64 + f * 8);
    }
    if (v0) {
      int ld = (int)(r0 & 127u);
      f32x4 a, bb;
      unpack8(row0, a, bb);
      float* ap = &acc[ld * 65 + f * 8];
      atomicAdd(ap + 0, a.x);
      atomicAdd(ap + 1, a.y);
      atomicAdd(ap + 2, a.z);
      atomicAdd(ap + 3, a.w);
      atomicAdd(ap + 4, bb.x);
      atomicAdd(ap + 5, bb.y);
      atomicAdd(ap + 6, bb.z);
      atomicAdd(ap + 7, bb.w);
      if (f == 0) atomicAdd(&cnt[ld], 1);
    }
    v0 = v1; r0 = r1; row0 = row1;
  }
  __syncthreads();
  // write-out: 4 threads per node, 16 feats each; fully coalesced
  int ln = t >> 2, q = t & 3;
  long n = (long)b * 128 + ln;
  float invd = 1.0f / fmaxf((float)cnt[ln], 1.0f);
  const float* ap = &acc[ln * 65 + q * 16];
  bf16x8 o0 = {(bf16)(ap[0] * invd), (bf16)(ap[1] * invd), (bf16)(ap[2] * invd),
               (bf16)(ap[3] * invd), (bf16)(ap[4] * invd), (bf16)(ap[5] * invd),
               (bf16)(ap[6] * invd), (bf16)(ap[7] * invd)};
  bf16x8 o1 = {(bf16)(ap[8] * invd), (bf16)(ap[9] * invd), (bf16)(ap[10] * invd),
               (bf16)(ap[11] * invd), (bf16)(ap[12] * invd), (bf16)(ap[13] * invd),
               (bf16)(ap[14] * invd), (bf16)(ap[15] * invd)};
  *(bf16x8*)(A1 + n * 128 + q * 16) = o0;
  *(bf16x8*)(A1 + n * 128 + q * 16 + 8) = o1;
  // root half: contiguous coalesced copy (pads: xb rows are zeroed)
  uint4 rv0 = *(const uint4*)(xb + n * 64 + q * 16);
  uint4 rv1 = *(const uint4*)(xb + n * 64 + q * 16 + 8);
  *(uint4*)(A1 + n * 128 + 64 + q * 16) = rv0;
  *(uint4*)(A1 + n * 128 + 64 + q * 16 + 8) = rv1;
}

// ---- fused GEMM1+GEMM2, v3 (unchanged, proven ~19-21 us) ----
__device__ inline int swzoff(int r, int x) {
  return r * 256 + (x ^ (((r & 3) << 6) ^ ((r & 7) << 4)));
}

__global__ __launch_bounds__(256) void fused_k(const bf16* __restrict__ A,
                                               const bf16* __restrict__ B1g,
                                               const bf16* __restrict__ B2g,
                                               const float* __restrict__ b1l,
                                               bf16* __restrict__ Ct,
                                               bf16* __restrict__ Cu, int T) {
  __shared__ __align__(16) char Asm[2][8192];  // 32 rows x 256 B, double-buffered
  __shared__ __align__(16) char Hsm[8192];     // 32 rows x 256 B
  int tid = threadIdx.x;
  int wave = tid >> 6, lane = tid & 63;
  int row = lane & 15, quad = lane >> 4;
  int cb = wave * 32;  // this wave's 32 output cols

  bf16x8 b1f[2][4], b2f[2][4];
#pragma unroll
  for (int jj = 0; jj < 2; jj++)
#pragma unroll
    for (int s = 0; s < 4; s++) {
      b1f[jj][s] = *(const bf16x8*)(B1g + (cb + jj * 16 + row) * 128 + s * 32 + quad * 8);
      b2f[jj][s] = *(const bf16x8*)(B2g + (cb + jj * 16 + row) * 128 + s * 32 + quad * 8);
    }
  float bias[2] = {b1l[cb + row], b1l[cb + 16 + row]};

  int srow = wave * 8 + quad;
  int schunk = row;  // 16 B chunk index within the 256 B row

  int t = blockIdx.x;
  {  // prologue: stage tile t into buf 0
    uint4 v0 = *(const uint4*)(A + ((long)t * 32 + srow) * 128 + schunk * 8);
    uint4 v1 = *(const uint4*)(A + ((long)t * 32 + srow + 4) * 128 + schunk * 8);
    *(uint4*)(Asm[0] + swzoff(srow, schunk * 16)) = v0;
    *(uint4*)(Asm[0] + swzoff(srow + 4, schunk * 16)) = v1;
  }
  __syncthreads();

  int p = 0;
  for (; t < T; t += (int)gridDim.x, p ^= 1) {
    int tn = t + (int)gridDim.x;
    bool pf = tn < T;
    uint4 v0 = {}, v1 = {};
    if (pf) {
      v0 = *(const uint4*)(A + ((long)tn * 32 + srow) * 128 + schunk * 8);
      v1 = *(const uint4*)(A + ((long)tn * 32 + srow + 4) * 128 + schunk * 8);
    }
    f32x4 acc1[2][2] = {};
#pragma unroll
    for (int s = 0; s < 4; s++) {
#pragma unroll
      for (int st = 0; st < 2; st++) {
        bf16x8 a = *(const bf16x8*)(Asm[p] + swzoff(st * 16 + row, s * 64 + quad * 16));
#pragma unroll
        for (int jj = 0; jj < 2; jj++)
          acc1[st][jj] = __builtin_amdgcn_mfma_f32_16x16x32_bf16(a, b1f[jj][s], acc1[st][jj], 0, 0, 0);
      }
    }
#pragma unroll
    for (int st = 0; st < 2; st++)
#pragma unroll
      for (int jj = 0; jj < 2; jj++)
#pragma unroll
        for (int i = 0; i < 4; i++) {
          float v = acc1[st][jj][i] + bias[jj];
          v = v > 0.0f ? v : 0.0f;
          *(bf16*)(Hsm + swzoff(st * 16 + quad * 4 + i, (cb + jj * 16 + row) * 2)) = (bf16)v;
        }
    __syncthreads();
    f32x4 acc2[2][2] = {};
#pragma unroll
    for (int s = 0; s < 4; s++) {
#pragma unroll
      for (int st = 0; st < 2; st++) {
        bf16x8 a = *(const bf16x8*)(Hsm + swzoff(st * 16 + row, s * 64 + quad * 16));
#pragma unroll
        for (int jj = 0; jj < 2; jj++)
          acc2[st][jj] = __builtin_amdgcn_mfma_f32_16x16x32_bf16(a, b2f[jj][s], acc2[st][jj], 0, 0, 0);
      }
    }
    bf16* outp = (wave < 2) ? Ct : Cu;
    int oc = cb + row - ((wave < 2) ? 0 : 64);
#pragma unroll
    for (int st = 0; st < 2; st++)
#pragma unroll
      for (int jj = 0; jj < 2; jj++)
#pragma unroll
        for (int i = 0; i < 4; i++) {
          long grow = (long)t * 32 + st * 16 + quad * 4 + i;
          outp[grow * 64 + oc + jj * 16] = (bf16)acc2[st][jj][i];
        }
    if (pf) {
      *(uint4*)(Asm[p ^ 1] + swzoff(srow, schunk * 16)) = v0;
      *(uint4*)(Asm[p ^ 1] + swzoff(srow + 4, schunk * 16)) = v1;
    }
    __syncthreads();
  }
}

// ---- R8: fused bucket aggregation, layer 2 (same mechanism as bagg1_k) ----
__global__ __launch_bounds__(512) void bagg2_k(const bf16* __restrict__ tmat,
                                               const bf16* __restrict__ umat,
                                               const unsigned* __restrict__ ebuf,
                                               const int* __restrict__ bsum,
                                               const float* __restrict__ b2l,
                                               float* __restrict__ out,
                                               int nb, int N, int E) {
  __shared__ float acc[128 * 65];
  __shared__ int cnt[128];
  int b = blockIdx.x, t = threadIdx.x;
  int s = bsum[b];
  int e = (b + 1 < nb) ? bsum[b + 1] : E;
  for (int i = t; i < 128 * 65; i += 512) acc[i] = 0.0f;
  if (t < 128) cnt[t] = 0;
  __syncthreads();
  int g = t >> 3, f = t & 7;
  bool v0 = (s + g) < e;
  unsigned r0 = 0;
  uint4 row0 = make_uint4(0u, 0u, 0u, 0u);
  if (v0) {
    r0 = ebuf[s + g];
    row0 = *(const uint4*)(tmat + (long)(r0 >> 7) * 64 + f * 8);
  }
  for (int base = s; base < e; base += 64) {
    int i1 = base + 64 + g;
    bool v1 = i1 < e;
    unsigned r1 = 0;
    uint4 row1 = make_uint4(0u, 0u, 0u, 0u);
    if (v1) {
      r1 = ebuf[i1];
      row1 = *(const uint4*)(tmat + (long)(r1 >> 7) * 64 + f * 8);
    }
    if (v0) {
      int ld = (int)(r0 & 127u);
      f32x4 a, bb;
      unpack8(row0, a, bb);
      float* ap = &acc[ld * 65 + f * 8];
      atomicAdd(ap + 0, a.x);
      atomicAdd(ap + 1, a.y);
      atomicAdd(ap + 2, a.z);
      atomicAdd(ap + 3, a.w);
      atomicAdd(ap + 4, bb.x);
      atomicAdd(ap + 5, bb.y);
      atomicAdd(ap + 6, bb.z);
      atomicAdd(ap + 7, bb.w);
      if (f == 0) atomicAdd(&cnt[ld], 1);
    }
    v0 = v1; r0 = r1; row0 = row1;
  }
  __syncthreads();
  int ln = t >> 2, q = t & 3;
  long n = (long)b * 128 + ln;
  if (n < N) {
    float invd = 1.0f / fmaxf((float)cnt[ln], 1.0f);
    const float* ap = &acc[ln * 65 + q * 16];
    uint4 uraw0 = *(const uint4*)(umat + n * 64 + q * 16);
    uint4 uraw1 = *(const uint4*)(umat + n * 64 + q * 16 + 8);
    float uf[16];
    {
      f32x4 a, c;
      unpack8(uraw0, a, c);
      uf[0] = a.x; uf[1] = a.y; uf[2] = a.z; uf[3] = a.w;
      uf[4] = c.x; uf[5] = c.y; uf[6] = c.z; uf[7] = c.w;
      unpack8(uraw1, a, c);
      uf[8] = a.x; uf[9] = a.y; uf[10] = a.z; uf[11] = a.w;
      uf[12] = c.x; uf[13] = c.y; uf[14] = c.z; uf[15] = c.w;
    }
    float ov[16];
#pragma unroll
    for (int k = 0; k < 16; k++) ov[k] = ap[k] * invd + b2l[q * 16 + k] + uf[k];
#pragma unroll
    for (int k = 0; k < 4; k++) {
      f32x4 o = {ov[4 * k], ov[4 * k + 1], ov[4 * k + 2], ov[4 * k + 3]};
      *(f32x4*)(out + n * 64 + q * 16 + k * 4) = o;
    }
  }
}

static inline size_t align256(size_t x) { return (x + 255) / 256 * 256; }

extern "C" void kernel_launch(void* const* d_in, const int* in_sizes, int n_in,
                              void* d_out, int out_size, void* d_ws, size_t ws_size,
                              hipStream_t stream) {
  const float* x = (const float*)d_in[0];
  const int* edge_index = (const int*)d_in[1];
  const float* W1l = (const float*)d_in[2];
  const float* b1l = (const float*)d_in[3];
  const float* W1r = (const float*)d_in[4];
  const float* W2l = (const float*)d_in[5];
  const float* b2l = (const float*)d_in[6];
  const float* W2r = (const float*)d_in[7];

  const int N = in_sizes[0] / 64;        // 100000
  const int E = in_sizes[1] / 2;         // 1200000
  const int Np = (N + 127) / 128 * 128;  // 100096
  const int nb = Np / 128;               // 782 buckets (<=1024 for scanB)
  const int M = nb * NBLK;               // hist elements (200192)

  const int* src = edge_index;
  const int* dst = edge_index + E;

  // ws layout (~65 MB; must not alias: fused_k reads A1 while writing tmat/umat)
  char* ws = (char*)d_ws;
  size_t off = 0;
  int* hist = (int*)(ws + off);           off += align256((size_t)M * 4);
  int* bsum = (int*)(ws + off);           off += align256((size_t)nb * 4);
  unsigned* ebuf = (unsigned*)(ws + off); off += align256((size_t)E * 4);
  bf16* xb = (bf16*)(ws + off);           off += align256((size_t)Np * 64 * 2);
  bf16* A1 = (bf16*)(ws + off);           off += align256((size_t)Np * 128 * 2);
  bf16* tmat = (bf16*)(ws + off);         off += align256((size_t)Np * 64 * 2);
  bf16* umat = (bf16*)(ws + off);         off += align256((size_t)Np * 64 * 2);
  bf16* B1 = (bf16*)(ws + off);           off += align256(128 * 128 * 2);
  bf16* B2 = (bf16*)(ws + off);           off += align256(128 * 128 * 2);
  float* out = (float*)d_out;

  const int cvtBlocks = (int)(((long)Np * 64 / 4 + 255) / 256);
  setup_k<<<NBLK + 128 + cvtBlocks, 256, 0, stream>>>(x, dst, W1l, W1r, W2l, W2r,
                                                      xb, B1, B2, hist, E, nb, N, Np);
  scanA_k<<<nb, 256, 0, stream>>>(hist, bsum);
  scanB_k<<<1, 1024, 0, stream>>>(bsum, nb);
  scat_k<<<NBLK, 512, 0, stream>>>(src, dst, hist, bsum, ebuf, E, nb);

  bagg1_k<<<nb, 512, 0, stream>>>(xb, ebuf, bsum, A1, nb, E);
  fused_k<<<1564, 256, 0, stream>>>(A1, B1, B2, b1l, tmat, umat, Np / 32);
  bagg2_k<<<nb, 512, 0, stream>>>(tmat, umat, ebuf, bsum, b2l, out, nb, N, E);
}

// Round 10
// 228.719 us; speedup vs baseline: 5.0519x; 5.0519x over previous
//
#include <hip/hip_runtime.h>
#include <hip/hip_bf16.h>

typedef __bf16 bf16;
typedef __attribute__((ext_vector_type(8))) __bf16 bf16x8;
typedef __attribute__((ext_vector_type(4))) float f32x4;

#define NBLK 256  // radix chunks == scanA block size (bucket-aligned scan)
#define CAP 3072  // per-bucket edge capacity for LDS sort (mean 1534, sigma 39 -> +39 sigma)

// unpack 8 packed bf16 (uint4) -> two f32x4
__device__ inline void unpack8(uint4 r, f32x4& a, f32x4& b) {
  a.x = __uint_as_float(r.x << 16);
  a.y = __uint_as_float(r.x & 0xffff0000u);
  a.z = __uint_as_float(r.y << 16);
  a.w = __uint_as_float(r.y & 0xffff0000u);
  b.x = __uint_as_float(r.z << 16);
  b.y = __uint_as_float(r.z & 0xffff0000u);
  b.z = __uint_as_float(r.w << 16);
  b.w = __uint_as_float(r.w & 0xffff0000u);
}

// slot load with neighbor index from LDS (broadcast ds_read for the 8 lanes of a row)
__device__ inline uint4 lslot(const bf16* __restrict__ tab, const int* lnbr,
                              int base, int e, int q, int fo) {
  int idx = base + q;
  uint4 r = make_uint4(0u, 0u, 0u, 0u);
  if (idx < e) {
    int j = lnbr[idx];
    r = *(const uint4*)(tab + (long)j * 64 + fo);
  }
  return r;
}

// Fused setup: blocks [0,NBLK) histogram; [NBLK,NBLK+128) pack B1/B2; rest cvt x->xb.
// (R7's direct-scatter REVERTED: random 4 B global stores -> 83 MB WRITE_SIZE for a
// 4.8 MB array (partial-line writeback amplification) at ~0.9 TB/s = 100 us.
// R8's f32-LDS-atomic agg REVERTED: f32 LDS atomicAdd is a CAS loop on gfx950 -> 512 us.)
__global__ __launch_bounds__(256) void setup_k(const float* __restrict__ x,
                                               const int* __restrict__ dst,
                                               const float* __restrict__ W1l,
                                               const float* __restrict__ W1r,
                                               const float* __restrict__ W2l,
                                               const float* __restrict__ W2r,
                                               bf16* __restrict__ xb,
                                               bf16* __restrict__ B1,
                                               bf16* __restrict__ B2,
                                               int* __restrict__ hist,
                                               int E, int nb, int N, int Np) {
  __shared__ int h[1024];
  int t = threadIdx.x;
  if (blockIdx.x < NBLK) {
    for (int i = t; i < nb; i += 256) h[i] = 0;
    __syncthreads();
    int chunk = (E + NBLK - 1) / NBLK;
    int s = blockIdx.x * chunk, e = min(E, s + chunk);
    for (int i = s + t; i < e; i += 256) atomicAdd(&h[dst[i] >> 7], 1);
    __syncthreads();
    for (int i = t; i < nb; i += 256) hist[(long)i * NBLK + blockIdx.x] = h[i];
  } else if (blockIdx.x < NBLK + 128) {
    int gid = (blockIdx.x - NBLK) * 256 + t;  // 0..32767
    if (gid < 16384) {
      int c = gid >> 7, k = gid & 127;
      float v = (k < 64) ? W1l[c * 64 + k] : W1r[c * 64 + (k - 64)];
      B1[gid] = (bf16)v;
    } else {
      int idx = gid - 16384;
      int n = idx >> 7, k = idx & 127;
      float v = (n < 64) ? W2l[n * 128 + k] : W2r[(n - 64) * 128 + k];
      B2[idx] = (bf16)v;
    }
  } else {
    int gid = (blockIdx.x - NBLK - 128) * 256 + t;  // one per 4 elems
    long base = (long)gid * 4;
    if (base >= (long)Np * 64) return;
    if (base < (long)N * 64) {
      f32x4 v = *(const f32x4*)(x + base);
      bf16 o[4] = {(bf16)v.x, (bf16)v.y, (bf16)v.z, (bf16)v.w};
      *(ulong1*)(xb + base) = *(ulong1*)o;
    } else {
      bf16 o[4] = {(bf16)0.0f, (bf16)0.0f, (bf16)0.0f, (bf16)0.0f};
      *(ulong1*)(xb + base) = *(ulong1*)o;
    }
  }
}

// scanA: one block per bucket; exclusive scan of the bucket's 256 chunk counts
// in place; bucket total -> bsum[bucket].
__global__ __launch_bounds__(256) void scanA_k(int* __restrict__ hist,
                                               int* __restrict__ bsum) {
  __shared__ int sd[256];
  int t = threadIdx.x;
  int idx = blockIdx.x * 256 + t;
  int v = hist[idx];
  sd[t] = v;
  __syncthreads();
#pragma unroll
  for (int off = 1; off < 256; off <<= 1) {
    int tv = (t >= off) ? sd[t - off] : 0;
    __syncthreads();
    if (t >= off) sd[t] += tv;
    __syncthreads();
  }
  hist[idx] = sd[t] - v;  // bucket-local exclusive prefix
  if (t == 255) bsum[blockIdx.x] = sd[255];
}

// scanB: single-block in-place exclusive scan of bsum (nb <= 1024).
__global__ __launch_bounds__(1024) void scanB_k(int* __restrict__ bsum, int nb) {
  __shared__ int sd[1024];
  int t = threadIdx.x;
  int v = (t < nb) ? bsum[t] : 0;
  sd[t] = v;
  __syncthreads();
#pragma unroll
  for (int off = 1; off < 1024; off <<= 1) {
    int tv = (t >= off) ? sd[t - off] : 0;
    __syncthreads();
    if (t >= off) sd[t] += tv;
    __syncthreads();
  }
  if (t < nb) bsum[t] = sd[t] - v;
}

// Pass 2: re-read chunk, LDS cursors = bsum[b] + hist[b][chunk], write packed
// records (src<<7 | local-dst) into bucket regions.
__global__ __launch_bounds__(512) void scat_k(const int* __restrict__ src,
                                              const int* __restrict__ dst,
                                              const int* __restrict__ hist,
                                              const int* __restrict__ bsum,
                                              unsigned* __restrict__ ebuf, int E, int nb) {
  __shared__ int cur[1024];
  for (int i = threadIdx.x; i < nb; i += 512)
    cur[i] = bsum[i] + hist[(long)i * NBLK + blockIdx.x];
  __syncthreads();
  int chunk = (E + NBLK - 1) / NBLK;
  int s = blockIdx.x * chunk, e = min(E, s + chunk);
  for (int i = s + threadIdx.x; i < e; i += 512) {
    int d = dst[i];
    int pos = atomicAdd(&cur[d >> 7], 1);
    ebuf[pos] = ((unsigned)src[i] << 7) | (unsigned)(d & 127);
  }
}

// ---- R9: bucket-fused sort+aggregate (csr_k's counting sort kept in LDS) ----
// Per bucket: int-LDS histogram + scan + scatter ebuf -> lnbr[CAP] (csr_k's
// exact algorithm, no global round trip), then 8 waves x 16 nodes run the
// proven R2 gather loop with neighbor ids from LDS. Eliminates csr_k, nbr and
// rowptr global traffic (~19 MB + a launch). Int LDS atomics only (native).
__device__ inline void bucket_sort(const unsigned* __restrict__ ebuf, int s, int e,
                                   int t, int* hcnt, int* hoff, int* lnbr) {
  if (t < 128) hcnt[t] = 0;
  __syncthreads();
  for (int i = s + t; i < e; i += 512) atomicAdd(&hcnt[ebuf[i] & 127u], 1);
  __syncthreads();
  if (t < 128) hoff[t + 1] = hcnt[t];
  if (t == 0) hoff[0] = 0;
  __syncthreads();
#pragma unroll
  for (int off = 1; off < 128; off <<= 1) {
    int v = (t < 128 && t >= off) ? hoff[t + 1 - off] : 0;
    __syncthreads();
    if (t < 128 && t >= off) hoff[t + 1] += v;
    __syncthreads();
  }
  if (t < 128) hcnt[t] = hoff[t];  // becomes cursor
  __syncthreads();
  for (int i = s + t; i < e; i += 512) {
    unsigned r = ebuf[i];
    int pos = atomicAdd(&hcnt[r & 127u], 1);
    lnbr[pos] = (int)(r >> 7);
  }
  __syncthreads();
}

__global__ __launch_bounds__(512) void bagg1_k(const bf16* __restrict__ xb,
                                               const unsigned* __restrict__ ebuf,
                                               const int* __restrict__ bsum,
                                               bf16* __restrict__ A1, int nb, int E) {
  __shared__ int hcnt[128];
  __shared__ int hoff[129];
  __shared__ int lnbr[CAP];
  int b = blockIdx.x, t = threadIdx.x;
  int s = bsum[b];
  int e = (b + 1 < nb) ? bsum[b + 1] : E;
  if (e - s > CAP) e = s + CAP;  // unreachable for this input (+39 sigma)
  bucket_sort(ebuf, s, e, t, hcnt, hoff, lnbr);

  int wave = t >> 6, lane = t & 63;
  int q = lane >> 3, f = lane & 7, fo = f * 8;
  int ls = hoff[wave * 16], le = hoff[wave * 16 + 1];
  uint4 c0 = lslot(xb, lnbr, ls, le, q, fo);
  uint4 c1 = lslot(xb, lnbr, ls + 8, le, q, fo);
  for (int mm = 0; mm < 16; mm++) {
    // prefetch next node's first two slot-loads (depth-1 cross-node pipeline)
    int lsN = 0, leN = 0;
    if (mm < 15) { lsN = hoff[wave * 16 + mm + 1]; leN = hoff[wave * 16 + mm + 2]; }
    uint4 n0 = lslot(xb, lnbr, lsN, leN, q, fo);
    uint4 n1 = lslot(xb, lnbr, lsN + 8, leN, q, fo);
    f32x4 sa = {0, 0, 0, 0}, sb = {0, 0, 0, 0};
    if (ls + 16 < le) {  // rare long-degree tail, depth-2 pipelined
      uint4 a0 = c0, a1 = c1;
      for (int i = ls + 16; i < le; i += 16) {
        uint4 t0 = lslot(xb, lnbr, i, le, q, fo);
        uint4 t1 = lslot(xb, lnbr, i + 8, le, q, fo);
        f32x4 a, bb;
        unpack8(a0, a, bb); sa += a; sb += bb;
        unpack8(a1, a, bb); sa += a; sb += bb;
        a0 = t0; a1 = t1;
      }
      c0 = a0; c1 = a1;
    }
    {
      f32x4 a, bb;
      unpack8(c0, a, bb); sa += a; sb += bb;
      unpack8(c1, a, bb); sa += a; sb += bb;
    }
    float v[8] = {sa.x, sa.y, sa.z, sa.w, sb.x, sb.y, sb.z, sb.w};
#pragma unroll
    for (int k = 0; k < 8; k++) {
      v[k] += __shfl_xor(v[k], 8);
      v[k] += __shfl_xor(v[k], 16);
      v[k] += __shfl_xor(v[k], 32);
    }
    long n = (long)b * 128 + wave * 16 + mm;
    float invd = 1.0f / fmaxf((float)(le - ls), 1.0f);
    if (q == 0) {
      bf16x8 o = {(bf16)(v[0] * invd), (bf16)(v[1] * invd), (bf16)(v[2] * invd),
                  (bf16)(v[3] * invd), (bf16)(v[4] * invd), (bf16)(v[5] * invd),
                  (bf16)(v[6] * invd), (bf16)(v[7] * invd)};
      *(bf16x8*)(A1 + n * 128 + fo) = o;
    } else if (q == 1) {
      uint4 rv = *(const uint4*)(xb + n * 64 + fo);  // pads: xb==0
      *(uint4*)(A1 + n * 128 + 64 + fo) = rv;
    }
    c0 = n0; c1 = n1; ls = lsN; le = leN;
  }
}

// ---- fused GEMM1+GEMM2, v3 (unchanged, proven ~19-21 us) ----
__device__ inline int swzoff(int r, int x) {
  return r * 256 + (x ^ (((r & 3) << 6) ^ ((r & 7) << 4)));
}

__global__ __launch_bounds__(256) void fused_k(const bf16* __restrict__ A,
                                               const bf16* __restrict__ B1g,
                                               const bf16* __restrict__ B2g,
                                               const float* __restrict__ b1l,
                                               bf16* __restrict__ Ct,
                                               bf16* __restrict__ Cu, int T) {
  __shared__ __align__(16) char Asm[2][8192];  // 32 rows x 256 B, double-buffered
  __shared__ __align__(16) char Hsm[8192];     // 32 rows x 256 B
  int tid = threadIdx.x;
  int wave = tid >> 6, lane = tid & 63;
  int row = lane & 15, quad = lane >> 4;
  int cb = wave * 32;  // this wave's 32 output cols

  bf16x8 b1f[2][4], b2f[2][4];
#pragma unroll
  for (int jj = 0; jj < 2; jj++)
#pragma unroll
    for (int s = 0; s < 4; s++) {
      b1f[jj][s] = *(const bf16x8*)(B1g + (cb + jj * 16 + row) * 128 + s * 32 + quad * 8);
      b2f[jj][s] = *(const bf16x8*)(B2g + (cb + jj * 16 + row) * 128 + s * 32 + quad * 8);
    }
  float bias[2] = {b1l[cb + row], b1l[cb + 16 + row]};

  int srow = wave * 8 + quad;
  int schunk = row;  // 16 B chunk index within the 256 B row

  int t = blockIdx.x;
  {  // prologue: stage tile t into buf 0
    uint4 v0 = *(const uint4*)(A + ((long)t * 32 + srow) * 128 + schunk * 8);
    uint4 v1 = *(const uint4*)(A + ((long)t * 32 + srow + 4) * 128 + schunk * 8);
    *(uint4*)(Asm[0] + swzoff(srow, schunk * 16)) = v0;
    *(uint4*)(Asm[0] + swzoff(srow + 4, schunk * 16)) = v1;
  }
  __syncthreads();

  int p = 0;
  for (; t < T; t += (int)gridDim.x, p ^= 1) {
    int tn = t + (int)gridDim.x;
    bool pf = tn < T;
    uint4 v0 = {}, v1 = {};
    if (pf) {
      v0 = *(const uint4*)(A + ((long)tn * 32 + srow) * 128 + schunk * 8);
      v1 = *(const uint4*)(A + ((long)tn * 32 + srow + 4) * 128 + schunk * 8);
    }
    f32x4 acc1[2][2] = {};
#pragma unroll
    for (int s = 0; s < 4; s++) {
#pragma unroll
      for (int st = 0; st < 2; st++) {
        bf16x8 a = *(const bf16x8*)(Asm[p] + swzoff(st * 16 + row, s * 64 + quad * 16));
#pragma unroll
        for (int jj = 0; jj < 2; jj++)
          acc1[st][jj] = __builtin_amdgcn_mfma_f32_16x16x32_bf16(a, b1f[jj][s], acc1[st][jj], 0, 0, 0);
      }
    }
#pragma unroll
    for (int st = 0; st < 2; st++)
#pragma unroll
      for (int jj = 0; jj < 2; jj++)
#pragma unroll
        for (int i = 0; i < 4; i++) {
          float v = acc1[st][jj][i] + bias[jj];
          v = v > 0.0f ? v : 0.0f;
          *(bf16*)(Hsm + swzoff(st * 16 + quad * 4 + i, (cb + jj * 16 + row) * 2)) = (bf16)v;
        }
    __syncthreads();
    f32x4 acc2[2][2] = {};
#pragma unroll
    for (int s = 0; s < 4; s++) {
#pragma unroll
      for (int st = 0; st < 2; st++) {
        bf16x8 a = *(const bf16x8*)(Hsm + swzoff(st * 16 + row, s * 64 + quad * 16));
#pragma unroll
        for (int jj = 0; jj < 2; jj++)
          acc2[st][jj] = __builtin_amdgcn_mfma_f32_16x16x32_bf16(a, b2f[jj][s], acc2[st][jj], 0, 0, 0);
      }
    }
    bf16* outp = (wave < 2) ? Ct : Cu;
    int oc = cb + row - ((wave < 2) ? 0 : 64);
#pragma unroll
    for (int st = 0; st < 2; st++)
#pragma unroll
      for (int jj = 0; jj < 2; jj++)
#pragma unroll
        for (int i = 0; i < 4; i++) {
          long grow = (long)t * 32 + st * 16 + quad * 4 + i;
          outp[grow * 64 + oc + jj * 16] = (bf16)acc2[st][jj][i];
        }
    if (pf) {
      *(uint4*)(Asm[p ^ 1] + swzoff(srow, schunk * 16)) = v0;
      *(uint4*)(Asm[p ^ 1] + swzoff(srow + 4, schunk * 16)) = v1;
    }
    __syncthreads();
  }
}

// ---- R9: bucket-fused sort+aggregate, layer 2 ----
__global__ __launch_bounds__(512) void bagg2_k(const bf16* __restrict__ tmat,
                                               const bf16* __restrict__ umat,
                                               const unsigned* __restrict__ ebuf,
                                               const int* __restrict__ bsum,
                                               const float* __restrict__ b2l,
                                               float* __restrict__ out,
                                               int nb, int N, int E) {
  __shared__ int hcnt[128];
  __shared__ int hoff[129];
  __shared__ int lnbr[CAP];
  int b = blockIdx.x, t = threadIdx.x;
  int s = bsum[b];
  int e = (b + 1 < nb) ? bsum[b + 1] : E;
  if (e - s > CAP) e = s + CAP;  // unreachable for this input
  bucket_sort(ebuf, s, e, t, hcnt, hoff, lnbr);

  int wave = t >> 6, lane = t & 63;
  int q = lane >> 3, f = lane & 7, fo = f * 8;
  int ls = hoff[wave * 16], le = hoff[wave * 16 + 1];
  uint4 c0 = lslot(tmat, lnbr, ls, le, q, fo);
  uint4 c1 = lslot(tmat, lnbr, ls + 8, le, q, fo);
  for (int mm = 0; mm < 16; mm++) {
    int lsN = 0, leN = 0;
    if (mm < 15) { lsN = hoff[wave * 16 + mm + 1]; leN = hoff[wave * 16 + mm + 2]; }
    uint4 n0 = lslot(tmat, lnbr, lsN, leN, q, fo);
    uint4 n1 = lslot(tmat, lnbr, lsN + 8, leN, q, fo);
    f32x4 sa = {0, 0, 0, 0}, sb = {0, 0, 0, 0};
    if (ls + 16 < le) {  // rare long-degree tail
      uint4 a0 = c0, a1 = c1;
      for (int i = ls + 16; i < le; i += 16) {
        uint4 t0 = lslot(tmat, lnbr, i, le, q, fo);
        uint4 t1 = lslot(tmat, lnbr, i + 8, le, q, fo);
        f32x4 a, bb;
        unpack8(a0, a, bb); sa += a; sb += bb;
        unpack8(a1, a, bb); sa += a; sb += bb;
        a0 = t0; a1 = t1;
      }
      c0 = a0; c1 = a1;
    }
    {
      f32x4 a, bb;
      unpack8(c0, a, bb); sa += a; sb += bb;
      unpack8(c1, a, bb); sa += a; sb += bb;
    }
    float v[8] = {sa.x, sa.y, sa.z, sa.w, sb.x, sb.y, sb.z, sb.w};
#pragma unroll
    for (int k = 0; k < 8; k++) {
      v[k] += __shfl_xor(v[k], 8);
      v[k] += __shfl_xor(v[k], 16);
      v[k] += __shfl_xor(v[k], 32);
    }
    long n = (long)b * 128 + wave * 16 + mm;
    if (q == 0 && n < N) {
      float invd = 1.0f / fmaxf((float)(le - ls), 1.0f);
      f32x4 b0 = *(const f32x4*)(b2l + fo);
      f32x4 b1 = *(const f32x4*)(b2l + fo + 4);
      f32x4 ua, ub;
      unpack8(*(const uint4*)(umat + n * 64 + fo), ua, ub);
      f32x4 o0, o1;
      o0.x = v[0] * invd + b0.x + ua.x;
      o0.y = v[1] * invd + b0.y + ua.y;
      o0.z = v[2] * invd + b0.z + ua.z;
      o0.w = v[3] * invd + b0.w + ua.w;
      o1.x = v[4] * invd + b1.x + ub.x;
      o1.y = v[5] * invd + b1.y + ub.y;
      o1.z = v[6] * invd + b1.z + ub.z;
      o1.w = v[7] * invd + b1.w + ub.w;
      *(f32x4*)(out + n * 64 + fo) = o0;
      *(f32x4*)(out + n * 64 + fo + 4) = o1;
    }
    c0 = n0; c1 = n1; ls = lsN; le = leN;
  }
}

static inline size_t align256(size_t x) { return (x + 255) / 256 * 256; }

extern "C" void kernel_launch(void* const* d_in, const int* in_sizes, int n_in,
                              void* d_out, int out_size, void* d_ws, size_t ws_size,
                              hipStream_t stream) {
  const float* x = (const float*)d_in[0];
  const int* edge_index = (const int*)d_in[1];
  const float* W1l = (const float*)d_in[2];
  const float* b1l = (const float*)d_in[3];
  const float* W1r = (const float*)d_in[4];
  const float* W2l = (const float*)d_in[5];
  const float* b2l = (const float*)d_in[6];
  const float* W2r = (const float*)d_in[7];

  const int N = in_sizes[0] / 64;        // 100000
  const int E = in_sizes[1] / 2;         // 1200000
  const int Np = (N + 127) / 128 * 128;  // 100096
  const int nb = Np / 128;               // 782 buckets (<=1024 for scanB)
  const int M = nb * NBLK;               // hist elements (200192)

  const int* src = edge_index;
  const int* dst = edge_index + E;

  // ws layout (~60 MB; must not alias: fused_k reads A1 while writing tmat/umat)
  char* ws = (char*)d_ws;
  size_t off = 0;
  int* hist = (int*)(ws + off);           off += align256((size_t)M * 4);
  int* bsum = (int*)(ws + off);           off += align256((size_t)nb * 4);
  unsigned* ebuf = (unsigned*)(ws + off); off += align256((size_t)E * 4);
  bf16* xb = (bf16*)(ws + off);           off += align256((size_t)Np * 64 * 2);
  bf16* A1 = (bf16*)(ws + off);           off += align256((size_t)Np * 128 * 2);
  bf16* tmat = (bf16*)(ws + off);         off += align256((size_t)Np * 64 * 2);
  bf16* umat = (bf16*)(ws + off);         off += align256((size_t)Np * 64 * 2);
  bf16* B1 = (bf16*)(ws + off);           off += align256(128 * 128 * 2);
  bf16* B2 = (bf16*)(ws + off);           off += align256(128 * 128 * 2);
  float* out = (float*)d_out;

  const int cvtBlocks = (int)(((long)Np * 64 / 4 + 255) / 256);
  setup_k<<<NBLK + 128 + cvtBlocks, 256, 0, stream>>>(x, dst, W1l, W1r, W2l, W2r,
                                                      xb, B1, B2, hist, E, nb, N, Np);
  scanA_k<<<nb, 256, 0, stream>>>(hist, bsum);
  scanB_k<<<1, 1024, 0, stream>>>(bsum, nb);
  scat_k<<<NBLK, 512, 0, stream>>>(src, dst, hist, bsum, ebuf, E, nb);

  bagg1_k<<<nb, 512, 0, stream>>>(xb, ebuf, bsum, A1, nb, E);
  fused_k<<<1564, 256, 0, stream>>>(A1, B1, B2, b1l, tmat, umat, Np / 32);
  bagg2_k<<<nb, 512, 0, stream>>>(tmat, umat, ebuf, bsum, b2l, out, nb, N, E);
}

// Round 11
// 218.577 us; speedup vs baseline: 5.2863x; 1.0464x over previous
//
#include <hip/hip_runtime.h>
#include <hip/hip_bf16.h>

typedef __bf16 bf16;
typedef __attribute__((ext_vector_type(8))) __bf16 bf16x8;
typedef __attribute__((ext_vector_type(4))) float f32x4;

#define NBLK 256  // radix chunks == scanA block size (bucket-aligned scan)
#define CAP 3072  // per-bucket edge capacity for LDS sort (mean 1534, sigma 39)

// unpack 8 packed bf16 (uint4) -> two f32x4
__device__ inline void unpack8(uint4 r, f32x4& a, f32x4& b) {
  a.x = __uint_as_float(r.x << 16);
  a.y = __uint_as_float(r.x & 0xffff0000u);
  a.z = __uint_as_float(r.y << 16);
  a.w = __uint_as_float(r.y & 0xffff0000u);
  b.x = __uint_as_float(r.z << 16);
  b.y = __uint_as_float(r.z & 0xffff0000u);
  b.z = __uint_as_float(r.w << 16);
  b.w = __uint_as_float(r.w & 0xffff0000u);
}

// predicated slot load, neighbor idx from global (agg2)
__device__ inline uint4 slot_load(const bf16* __restrict__ tab, const int* __restrict__ nbr,
                                  int base, int e, int q, int fo) {
  int idx = base + q;
  uint4 r = make_uint4(0u, 0u, 0u, 0u);
  if (idx < e) {
    int j = nbr[idx];
    r = *(const uint4*)(tab + (long)j * 64 + fo);
  }
  return r;
}

// predicated slot load, neighbor idx from LDS (csragg1)
__device__ inline uint4 lslot(const bf16* __restrict__ tab, const int* lnbr,
                              int base, int e, int q, int fo) {
  int idx = base + q;
  uint4 r = make_uint4(0u, 0u, 0u, 0u);
  if (idx < e) {
    int j = lnbr[idx];
    r = *(const uint4*)(tab + (long)j * 64 + fo);
  }
  return r;
}

// Fused setup: blocks [0,NBLK) histogram; [NBLK,NBLK+128) pack B1/B2; rest cvt x->xb.
// (Ledger: R7 direct-scatter REVERTED — random 4 B global stores -> 17x write
// amplification, 100 us. R8 f32-LDS-atomic agg REVERTED — CAS loop, 512 us.
// R10 dual-LDS-sort REVERTED — bagg2's redundant sort lost 9 us.)
__global__ __launch_bounds__(256) void setup_k(const float* __restrict__ x,
                                               const int* __restrict__ dst,
                                               const float* __restrict__ W1l,
                                               const float* __restrict__ W1r,
                                               const float* __restrict__ W2l,
                                               const float* __restrict__ W2r,
                                               bf16* __restrict__ xb,
                                               bf16* __restrict__ B1,
                                               bf16* __restrict__ B2,
                                               int* __restrict__ hist,
                                               int E, int nb, int N, int Np) {
  __shared__ int h[1024];
  int t = threadIdx.x;
  if (blockIdx.x < NBLK) {
    for (int i = t; i < nb; i += 256) h[i] = 0;
    __syncthreads();
    int chunk = (E + NBLK - 1) / NBLK;
    int s = blockIdx.x * chunk, e = min(E, s + chunk);
    for (int i = s + t; i < e; i += 256) atomicAdd(&h[dst[i] >> 7], 1);
    __syncthreads();
    for (int i = t; i < nb; i += 256) hist[(long)i * NBLK + blockIdx.x] = h[i];
  } else if (blockIdx.x < NBLK + 128) {
    int gid = (blockIdx.x - NBLK) * 256 + t;  // 0..32767
    if (gid < 16384) {
      int c = gid >> 7, k = gid & 127;
      float v = (k < 64) ? W1l[c * 64 + k] : W1r[c * 64 + (k - 64)];
      B1[gid] = (bf16)v;
    } else {
      int idx = gid - 16384;
      int n = idx >> 7, k = idx & 127;
      float v = (n < 64) ? W2l[n * 128 + k] : W2r[(n - 64) * 128 + k];
      B2[idx] = (bf16)v;
    }
  } else {
    int gid = (blockIdx.x - NBLK - 128) * 256 + t;  // one per 4 elems
    long base = (long)gid * 4;
    if (base >= (long)Np * 64) return;
    if (base < (long)N * 64) {
      f32x4 v = *(const f32x4*)(x + base);
      bf16 o[4] = {(bf16)v.x, (bf16)v.y, (bf16)v.z, (bf16)v.w};
      *(ulong1*)(xb + base) = *(ulong1*)o;
    } else {
      bf16 o[4] = {(bf16)0.0f, (bf16)0.0f, (bf16)0.0f, (bf16)0.0f};
      *(ulong1*)(xb + base) = *(ulong1*)o;
    }
  }
}

// scanA: one block per bucket; exclusive scan of the bucket's 256 chunk counts
// in place; bucket total -> bsum[bucket].
__global__ __launch_bounds__(256) void scanA_k(int* __restrict__ hist,
                                               int* __restrict__ bsum) {
  __shared__ int sd[256];
  int t = threadIdx.x;
  int idx = blockIdx.x * 256 + t;
  int v = hist[idx];
  sd[t] = v;
  __syncthreads();
#pragma unroll
  for (int off = 1; off < 256; off <<= 1) {
    int tv = (t >= off) ? sd[t - off] : 0;
    __syncthreads();
    if (t >= off) sd[t] += tv;
    __syncthreads();
  }
  hist[idx] = sd[t] - v;  // bucket-local exclusive prefix
  if (t == 255) bsum[blockIdx.x] = sd[255];
}

// scanB: single-block in-place exclusive scan of bsum (nb <= 1024).
__global__ __launch_bounds__(1024) void scanB_k(int* __restrict__ bsum, int nb) {
  __shared__ int sd[1024];
  int t = threadIdx.x;
  int v = (t < nb) ? bsum[t] : 0;
  sd[t] = v;
  __syncthreads();
#pragma unroll
  for (int off = 1; off < 1024; off <<= 1) {
    int tv = (t >= off) ? sd[t - off] : 0;
    __syncthreads();
    if (t >= off) sd[t] += tv;
    __syncthreads();
  }
  if (t < nb) bsum[t] = sd[t] - v;
}

// Pass 2: re-read chunk, LDS cursors = bsum[b] + hist[b][chunk], write packed
// records (src<<7 | local-dst) into bucket regions.
__global__ __launch_bounds__(512) void scat_k(const int* __restrict__ src,
                                              const int* __restrict__ dst,
                                              const int* __restrict__ hist,
                                              const int* __restrict__ bsum,
                                              unsigned* __restrict__ ebuf, int E, int nb) {
  __shared__ int cur[1024];
  for (int i = threadIdx.x; i < nb; i += 512)
    cur[i] = bsum[i] + hist[(long)i * NBLK + blockIdx.x];
  __syncthreads();
  int chunk = (E + NBLK - 1) / NBLK;
  int s = blockIdx.x * chunk, e = min(E, s + chunk);
  for (int i = s + threadIdx.x; i < e; i += 512) {
    int d = dst[i];
    int pos = atomicAdd(&cur[d >> 7], 1);
    ebuf[pos] = ((unsigned)src[i] << 7) | (unsigned)(d & 127);
  }
}

// in-LDS counting sort of one bucket (int atomics only — the native fast path)
__device__ inline void bucket_sort(const unsigned* __restrict__ ebuf, int s, int e,
                                   int t, int* hcnt, int* hoff, int* lnbr) {
  if (t < 128) hcnt[t] = 0;
  __syncthreads();
  for (int i = s + t; i < e; i += 512) atomicAdd(&hcnt[ebuf[i] & 127u], 1);
  __syncthreads();
  if (t < 128) hoff[t + 1] = hcnt[t];
  if (t == 0) hoff[0] = 0;
  __syncthreads();
#pragma unroll
  for (int off = 1; off < 128; off <<= 1) {
    int v = (t < 128 && t >= off) ? hoff[t + 1 - off] : 0;
    __syncthreads();
    if (t < 128 && t >= off) hoff[t + 1] += v;
    __syncthreads();
  }
  if (t < 128) hcnt[t] = hoff[t];  // becomes cursor
  __syncthreads();
  for (int i = s + t; i < e; i += 512) {
    unsigned r = ebuf[i];
    int pos = atomicAdd(&hcnt[r & 127u], 1);
    lnbr[pos] = (int)(r >> 7);
  }
  __syncthreads();
}

// ---- R11: csr_k + agg1 fused. R10 measured the LDS sort+agg loop at 50 us
// (= csr 15 + agg1 36 - launch gap); here it ALSO emits nbr/rowptr (coalesced,
// bucket-contiguous — csr_k's exact write pattern) for agg2, and A1 shrinks to
// the 64-feat agg mean only (root half read by fused_k straight from xb:
// -12.8 MB writes).
__global__ __launch_bounds__(512) void csragg1_k(const bf16* __restrict__ xb,
                                                 const unsigned* __restrict__ ebuf,
                                                 const int* __restrict__ bsum,
                                                 int* __restrict__ rowptr,
                                                 int* __restrict__ nbr,
                                                 bf16* __restrict__ A1,
                                                 int nb, int Np, int E) {
  __shared__ int hcnt[128];
  __shared__ int hoff[129];
  __shared__ int lnbr[CAP];
  int b = blockIdx.x, t = threadIdx.x;
  int s = bsum[b];
  int e = (b + 1 < nb) ? bsum[b + 1] : E;
  if (e - s > CAP) e = s + CAP;  // unreachable for this input
  bucket_sort(ebuf, s, e, t, hcnt, hoff, lnbr);

  // emit global CSR for agg2 (coalesced, bucket-contiguous)
  if (t < 128) rowptr[b * 128 + t] = s + hoff[t];
  if (b == nb - 1 && t == 128) rowptr[Np] = E;
  for (int i = t; i < e - s; i += 512) nbr[s + i] = lnbr[i];

  int wave = t >> 6, lane = t & 63;
  int q = lane >> 3, f = lane & 7, fo = f * 8;
  int ls = hoff[wave * 16], le = hoff[wave * 16 + 1];
  uint4 c0 = lslot(xb, lnbr, ls, le, q, fo);
  uint4 c1 = lslot(xb, lnbr, ls + 8, le, q, fo);
  for (int mm = 0; mm < 16; mm++) {
    int lsN = 0, leN = 0;
    if (mm < 15) { lsN = hoff[wave * 16 + mm + 1]; leN = hoff[wave * 16 + mm + 2]; }
    uint4 n0 = lslot(xb, lnbr, lsN, leN, q, fo);
    uint4 n1 = lslot(xb, lnbr, lsN + 8, leN, q, fo);
    f32x4 sa = {0, 0, 0, 0}, sb = {0, 0, 0, 0};
    if (ls + 16 < le) {  // rare long-degree tail, depth-2 pipelined
      uint4 a0 = c0, a1 = c1;
      for (int i = ls + 16; i < le; i += 16) {
        uint4 t0 = lslot(xb, lnbr, i, le, q, fo);
        uint4 t1 = lslot(xb, lnbr, i + 8, le, q, fo);
        f32x4 a, bb;
        unpack8(a0, a, bb); sa += a; sb += bb;
        unpack8(a1, a, bb); sa += a; sb += bb;
        a0 = t0; a1 = t1;
      }
      c0 = a0; c1 = a1;
    }
    {
      f32x4 a, bb;
      unpack8(c0, a, bb); sa += a; sb += bb;
      unpack8(c1, a, bb); sa += a; sb += bb;
    }
    float v[8] = {sa.x, sa.y, sa.z, sa.w, sb.x, sb.y, sb.z, sb.w};
#pragma unroll
    for (int k = 0; k < 8; k++) {
      v[k] += __shfl_xor(v[k], 8);
      v[k] += __shfl_xor(v[k], 16);
      v[k] += __shfl_xor(v[k], 32);
    }
    long n = (long)b * 128 + wave * 16 + mm;
    float invd = 1.0f / fmaxf((float)(le - ls), 1.0f);
    if (q == 0) {
      bf16x8 o = {(bf16)(v[0] * invd), (bf16)(v[1] * invd), (bf16)(v[2] * invd),
                  (bf16)(v[3] * invd), (bf16)(v[4] * invd), (bf16)(v[5] * invd),
                  (bf16)(v[6] * invd), (bf16)(v[7] * invd)};
      *(bf16x8*)(A1 + n * 64 + fo) = o;
    }
    c0 = n0; c1 = n1; ls = lsN; le = leN;
  }
}

// ---- fused GEMM1+GEMM2, v4: A-row = [A1 64-feat agg | xb 64-feat root] ----
// (register-persistent B + grid-stride tiles; proven ~20 us structure)
__device__ inline int swzoff(int r, int x) {
  return r * 256 + (x ^ (((r & 3) << 6) ^ ((r & 7) << 4)));
}

__global__ __launch_bounds__(256) void fused_k(const bf16* __restrict__ A,
                                               const bf16* __restrict__ xb,
                                               const bf16* __restrict__ B1g,
                                               const bf16* __restrict__ B2g,
                                               const float* __restrict__ b1l,
                                               bf16* __restrict__ Ct,
                                               bf16* __restrict__ Cu, int T) {
  __shared__ __align__(16) char Asm[2][8192];  // 32 rows x 256 B, double-buffered
  __shared__ __align__(16) char Hsm[8192];     // 32 rows x 256 B
  int tid = threadIdx.x;
  int wave = tid >> 6, lane = tid & 63;
  int row = lane & 15, quad = lane >> 4;
  int cb = wave * 32;  // this wave's 32 output cols

  bf16x8 b1f[2][4], b2f[2][4];
#pragma unroll
  for (int jj = 0; jj < 2; jj++)
#pragma unroll
    for (int s = 0; s < 4; s++) {
      b1f[jj][s] = *(const bf16x8*)(B1g + (cb + jj * 16 + row) * 128 + s * 32 + quad * 8);
      b2f[jj][s] = *(const bf16x8*)(B2g + (cb + jj * 16 + row) * 128 + s * 32 + quad * 8);
    }
  float bias[2] = {b1l[cb + row], b1l[cb + 16 + row]};

  // A staging: logical row = [A(64) | xb(64)]; chunks 0-7 from A, 8-15 from xb
  int srow = wave * 8 + quad;
  int schunk = row;                                   // 16 B chunk in 256 B row
  const bf16* atab = (schunk < 8) ? A : xb;           // per-lane table select
  int co = (schunk & 7) * 8;                          // element offset in 64-wide row

  int t = blockIdx.x;
  {  // prologue: stage tile t into buf 0
    long rb = (long)t * 32 + srow;
    uint4 v0 = *(const uint4*)(atab + rb * 64 + co);
    uint4 v1 = *(const uint4*)(atab + (rb + 4) * 64 + co);
    *(uint4*)(Asm[0] + swzoff(srow, schunk * 16)) = v0;
    *(uint4*)(Asm[0] + swzoff(srow + 4, schunk * 16)) = v1;
  }
  __syncthreads();

  int p = 0;
  for (; t < T; t += (int)gridDim.x, p ^= 1) {
    int tn = t + (int)gridDim.x;
    bool pf = tn < T;
    uint4 v0 = {}, v1 = {};
    if (pf) {  // issue next-tile loads now; consumed after the stores
      long rb = (long)tn * 32 + srow;
      v0 = *(const uint4*)(atab + rb * 64 + co);
      v1 = *(const uint4*)(atab + (rb + 4) * 64 + co);
    }
    // ---- GEMM1: 32 rows x 32 cols, K=128, A from LDS, B1 from regs ----
    f32x4 acc1[2][2] = {};
#pragma unroll
    for (int s = 0; s < 4; s++) {
#pragma unroll
      for (int st = 0; st < 2; st++) {
        bf16x8 a = *(const bf16x8*)(Asm[p] + swzoff(st * 16 + row, s * 64 + quad * 16));
#pragma unroll
        for (int jj = 0; jj < 2; jj++)
          acc1[st][jj] = __builtin_amdgcn_mfma_f32_16x16x32_bf16(a, b1f[jj][s], acc1[st][jj], 0, 0, 0);
      }
    }
    // epilogue 1: bias+relu -> Hsm
#pragma unroll
    for (int st = 0; st < 2; st++)
#pragma unroll
      for (int jj = 0; jj < 2; jj++)
#pragma unroll
        for (int i = 0; i < 4; i++) {
          float v = acc1[st][jj][i] + bias[jj];
          v = v > 0.0f ? v : 0.0f;
          *(bf16*)(Hsm + swzoff(st * 16 + quad * 4 + i, (cb + jj * 16 + row) * 2)) = (bf16)v;
        }
    __syncthreads();  // h visible to all waves (K exchange)
    // ---- GEMM2 ----
    f32x4 acc2[2][2] = {};
#pragma unroll
    for (int s = 0; s < 4; s++) {
#pragma unroll
      for (int st = 0; st < 2; st++) {
        bf16x8 a = *(const bf16x8*)(Hsm + swzoff(st * 16 + row, s * 64 + quad * 16));
#pragma unroll
        for (int jj = 0; jj < 2; jj++)
          acc2[st][jj] = __builtin_amdgcn_mfma_f32_16x16x32_bf16(a, b2f[jj][s], acc2[st][jj], 0, 0, 0);
      }
    }
    // epilogue 2: waves 0,1 -> Ct cols 0..63; waves 2,3 -> Cu cols 0..63
    bf16* outp = (wave < 2) ? Ct : Cu;
    int oc = cb + row - ((wave < 2) ? 0 : 64);
#pragma unroll
    for (int st = 0; st < 2; st++)
#pragma unroll
      for (int jj = 0; jj < 2; jj++)
#pragma unroll
        for (int i = 0; i < 4; i++) {
          long grow = (long)t * 32 + st * 16 + quad * 4 + i;
          outp[grow * 64 + oc + jj * 16] = (bf16)acc2[st][jj][i];
        }
    if (pf) {  // stage next tile into the other buffer
      *(uint4*)(Asm[p ^ 1] + swzoff(srow, schunk * 16)) = v0;
      *(uint4*)(Asm[p ^ 1] + swzoff(srow + 4, schunk * 16)) = v1;
    }
    __syncthreads();  // A(t+1) visible; also fences h reads vs next h writes
  }
}

// ---- layer 2 aggregation: R2 wave-per-node (proven 41.0 us, VGPR 20, occ
// 62%). Batching attempts (R4/R5) regressed: compiler sinks prefetch gathers.
// Per-edge cost = one random 128 B line miss -> MSHR x latency floor.
__global__ __launch_bounds__(256) void agg2_k(const bf16* __restrict__ tmat,
                                              const bf16* __restrict__ umat,
                                              const int* __restrict__ rowptr,
                                              const int* __restrict__ nbr,
                                              const float* __restrict__ b2l,
                                              float* __restrict__ out, int N) {
  int wave = threadIdx.x >> 6, lane = threadIdx.x & 63;
  int n = blockIdx.x * 4 + wave;
  if (n >= N) return;
  int s = rowptr[n], e = rowptr[n + 1];
  int q = lane >> 3, f = lane & 7;
  int fo = f * 8;
  f32x4 sa = {0, 0, 0, 0}, sb = {0, 0, 0, 0};
  uint4 c0 = slot_load(tmat, nbr, s, e, q, fo);
  uint4 c1 = slot_load(tmat, nbr, s + 8, e, q, fo);
  int i = s + 16;
  for (; i < e; i += 16) {
    uint4 n0 = slot_load(tmat, nbr, i, e, q, fo);
    uint4 n1 = slot_load(tmat, nbr, i + 8, e, q, fo);
    f32x4 a, b;
    unpack8(c0, a, b); sa += a; sb += b;
    unpack8(c1, a, b); sa += a; sb += b;
    c0 = n0; c1 = n1;
  }
  {
    f32x4 a, b;
    unpack8(c0, a, b); sa += a; sb += b;
    unpack8(c1, a, b); sa += a; sb += b;
  }
  float v[8] = {sa.x, sa.y, sa.z, sa.w, sb.x, sb.y, sb.z, sb.w};
#pragma unroll
  for (int k = 0; k < 8; k++) {
    v[k] += __shfl_xor(v[k], 8);
    v[k] += __shfl_xor(v[k], 16);
    v[k] += __shfl_xor(v[k], 32);
  }
  if (q == 0) {
    float invd = 1.0f / fmaxf((float)(e - s), 1.0f);
    f32x4 b0 = *(const f32x4*)(b2l + fo);
    f32x4 b1 = *(const f32x4*)(b2l + fo + 4);
    f32x4 ua, ub;
    unpack8(*(const uint4*)(umat + n * 64 + fo), ua, ub);
    f32x4 o0, o1;
    o0.x = v[0] * invd + b0.x + ua.x;
    o0.y = v[1] * invd + b0.y + ua.y;
    o0.z = v[2] * invd + b0.z + ua.z;
    o0.w = v[3] * invd + b0.w + ua.w;
    o1.x = v[4] * invd + b1.x + ub.x;
    o1.y = v[5] * invd + b1.y + ub.y;
    o1.z = v[6] * invd + b1.z + ub.z;
    o1.w = v[7] * invd + b1.w + ub.w;
    *(f32x4*)(out + n * 64 + fo) = o0;
    *(f32x4*)(out + n * 64 + fo + 4) = o1;
  }
}

static inline size_t align256(size_t x) { return (x + 255) / 256 * 256; }

extern "C" void kernel_launch(void* const* d_in, const int* in_sizes, int n_in,
                              void* d_out, int out_size, void* d_ws, size_t ws_size,
                              hipStream_t stream) {
  const float* x = (const float*)d_in[0];
  const int* edge_index = (const int*)d_in[1];
  const float* W1l = (const float*)d_in[2];
  const float* b1l = (const float*)d_in[3];
  const float* W1r = (const float*)d_in[4];
  const float* W2l = (const float*)d_in[5];
  const float* b2l = (const float*)d_in[6];
  const float* W2r = (const float*)d_in[7];

  const int N = in_sizes[0] / 64;        // 100000
  const int E = in_sizes[1] / 2;         // 1200000
  const int Np = (N + 127) / 128 * 128;  // 100096
  const int nb = Np / 128;               // 782 buckets (<=1024 for scanB)
  const int M = nb * NBLK;               // hist elements (200192)

  const int* src = edge_index;
  const int* dst = edge_index + E;

  // ws layout (~60 MB; must not alias: fused_k reads A1/xb while writing tmat/umat)
  char* ws = (char*)d_ws;
  size_t off = 0;
  int* hist = (int*)(ws + off);           off += align256((size_t)M * 4);
  int* bsum = (int*)(ws + off);           off += align256((size_t)nb * 4);
  int* rowptr = (int*)(ws + off);         off += align256((size_t)(Np + 1) * 4);
  unsigned* ebuf = (unsigned*)(ws + off); off += align256((size_t)E * 4);
  int* nbr = (int*)(ws + off);            off += align256((size_t)E * 4);
  bf16* xb = (bf16*)(ws + off);           off += align256((size_t)Np * 64 * 2);
  bf16* A1 = (bf16*)(ws + off);           off += align256((size_t)Np * 64 * 2);
  bf16* tmat = (bf16*)(ws + off);         off += align256((size_t)Np * 64 * 2);
  bf16* umat = (bf16*)(ws + off);         off += align256((size_t)Np * 64 * 2);
  bf16* B1 = (bf16*)(ws + off);           off += align256(128 * 128 * 2);
  bf16* B2 = (bf16*)(ws + off);           off += align256(128 * 128 * 2);
  float* out = (float*)d_out;

  const int cvtBlocks = (int)(((long)Np * 64 / 4 + 255) / 256);
  setup_k<<<NBLK + 128 + cvtBlocks, 256, 0, stream>>>(x, dst, W1l, W1r, W2l, W2r,
                                                      xb, B1, B2, hist, E, nb, N, Np);
  scanA_k<<<nb, 256, 0, stream>>>(hist, bsum);
  scanB_k<<<1, 1024, 0, stream>>>(bsum, nb);
  scat_k<<<NBLK, 512, 0, stream>>>(src, dst, hist, bsum, ebuf, E, nb);

  csragg1_k<<<nb, 512, 0, stream>>>(xb, ebuf, bsum, rowptr, nbr, A1, nb, Np, E);
  fused_k<<<1564, 256, 0, stream>>>(A1, xb, B1, B2, b1l, tmat, umat, Np / 32);
  agg2_k<<<(N + 3) / 4, 256, 0, stream>>>(tmat, umat, rowptr, nbr, b2l, out, N);
}